// Round 1
// baseline (353.445 us; speedup 1.0000x reference)
//
#include <hip/hip_runtime.h>

// Problem constants (match reference)
constexpr int NB = 4, NC = 96, NH = 256, NW = 256;
constexpr int NK = 288;           // 3*NC
constexpr int HW = NH * NW;       // 65536

typedef __attribute__((ext_vector_type(8))) short short8;   // 8 bf16
typedef __attribute__((ext_vector_type(4))) float f32x4;    // 4 f32 acc

__device__ __forceinline__ unsigned short f2bf(float f) {
    unsigned int u = __builtin_bit_cast(unsigned int, f);
    u += 0x7FFFu + ((u >> 16) & 1u);        // round-to-nearest-even (inputs finite)
    return (unsigned short)(u >> 16);
}

__device__ __forceinline__ float ffm_sel(float a, float b) {
    // mask*a + (1-mask)*b with mask = |a| >= |b|
    return (__builtin_fabsf(a) >= __builtin_fabsf(b)) ? a : b;
}

// Fused: DWT(x1,x2,x3) -> A-avg/B/C/D-ffm -> IDWT -> concat[xr,x2,x3] -> 1x1 conv (bf16 MFMA)
// Block: 256 thr (4 waves). Tile: 2 rows x 32 cols = 64 px, all 96 output channels.
// K processed as 3 super-chunks of 32 input channels; each super-chunk stages
// 3 K-sections (xr, x2, x3) so every input byte is read exactly once.
__global__ __launch_bounds__(256) void dwt_fused_kernel(
    const float* __restrict__ x1, const float* __restrict__ x2,
    const float* __restrict__ x3, const float* __restrict__ w_out,
    float* __restrict__ out)
{
    // rows padded 32 -> 40 bf16 (80B stride, 16B-aligned b128 reads, 2-way banks = free)
    __shared__ __align__(16) unsigned short y_lds[3][64][40];  // [sec][px][k]  15360 B
    __shared__ __align__(16) unsigned short w_lds[3][96][40];  // [sec][o][k]   23040 B

    const int tid  = threadIdx.x;
    const int wv   = tid >> 6;
    const int lane = tid & 63;
    const int n    = lane & 15;   // MFMA: col of C/D (=pixel), row-sel of frags
    const int q    = lane >> 4;   // quad
    const int bx = blockIdx.x, by = blockIdx.y, bz = blockIdx.z;

    f32x4 acc[6];
#pragma unroll
    for (int t = 0; t < 6; ++t) acc[t] = (f32x4){0.f, 0.f, 0.f, 0.f};

    // staging thread mapping: channel-pair cp (0..15), col-block cb (0..15)
    const int cp = tid >> 4, cb = tid & 15;
    const int gx = bx * 32 + 2 * cb;   // even global col
    const int h0 = by * 2;             // even global row

    for (int s = 0; s < 3; ++s) {
        const int ch0 = 32 * s;

        // ---- stage w chunk: w_out[o][sec*96 + ch0 .. +32) -> bf16 LDS ----
#pragma unroll
        for (int j = 0; j < 9; ++j) {
            int i = tid + (j << 8);            // 0..2303
            int row = i >> 3, part = i & 7;    // row: (sec,o), part: 4-float group
            int sec = (row >= 192) ? 2 : (row >= 96 ? 1 : 0);
            int o = row - sec * 96;
            float4 v = *(const float4*)(w_out + (size_t)o * NK + sec * 96 + ch0 + part * 4);
            *(ushort4*)&w_lds[sec][o][part * 4] =
                make_ushort4(f2bf(v.x), f2bf(v.y), f2bf(v.z), f2bf(v.w));
        }

        // ---- stage x: load once, DWT->merge->IDWT (f32), emit 3 bf16 sections ----
        float xr[2][4], r2[2][4], r3[2][4];
#pragma unroll
        for (int dc = 0; dc < 2; ++dc) {
            const int c = ch0 + 2 * cp + dc;
            const size_t base = ((size_t)(bz * NC + c) * NH + h0) * NW + gx;
            float2 a1 = *(const float2*)(x1 + base);
            float2 b1 = *(const float2*)(x1 + base + NW);
            float2 a2 = *(const float2*)(x2 + base);
            float2 b2 = *(const float2*)(x2 + base + NW);
            float2 a3 = *(const float2*)(x3 + base);
            float2 b3 = *(const float2*)(x3 + base + NW);

            float A1, B1, C1, D1, A2, B2, C2, D2, A3, B3, C3, D3;
#define DWT4(aa, bb, Ao, Bo, Co, Do)                                          \
            { float e = aa.x * 0.5f, f = bb.x * 0.5f,                          \
                    g = aa.y * 0.5f, h = bb.y * 0.5f;                          \
              Ao = ((e + f) + g) + h;  Bo = (((-e) - f) + g) + h;              \
              Co = (((-e) + f) - g) + h; Do = ((e - f) - g) + h; }
            DWT4(a1, b1, A1, B1, C1, D1)
            DWT4(a2, b2, A2, B2, C2, D2)
            DWT4(a3, b3, A3, B3, C3, D3)
#undef DWT4
            float A  = (A1 + A2 + A3) / 3.0f;
            float Bf = ffm_sel(ffm_sel(B1, B2), B3);
            float Cf = ffm_sel(ffm_sel(C1, C2), C3);
            float Df = ffm_sel(ffm_sel(D1, D2), D3);
            // positions: 0:(r0,even) 1:(r1,even) 2:(r0,odd) 3:(r1,odd)
            xr[dc][0] = (((A - Bf) - Cf) + Df) * 0.5f;
            xr[dc][1] = (((A - Bf) + Cf) - Df) * 0.5f;
            xr[dc][2] = (((A + Bf) - Cf) - Df) * 0.5f;
            xr[dc][3] = (((A + Bf) + Cf) + Df) * 0.5f;
            r2[dc][0] = a2.x; r2[dc][1] = b2.x; r2[dc][2] = a2.y; r2[dc][3] = b2.y;
            r3[dc][0] = a3.x; r3[dc][1] = b3.x; r3[dc][2] = a3.y; r3[dc][3] = b3.y;
        }
        const int pxs[4] = {2 * cb, 32 + 2 * cb, 2 * cb + 1, 33 + 2 * cb};
#pragma unroll
        for (int p = 0; p < 4; ++p) {
            *(ushort2*)&y_lds[0][pxs[p]][2 * cp] = make_ushort2(f2bf(xr[0][p]), f2bf(xr[1][p]));
            *(ushort2*)&y_lds[1][pxs[p]][2 * cp] = make_ushort2(f2bf(r2[0][p]), f2bf(r2[1][p]));
            *(ushort2*)&y_lds[2][pxs[p]][2 * cp] = make_ushort2(f2bf(r3[0][p]), f2bf(r3[1][p]));
        }

        __syncthreads();

        // ---- MFMA: D[o][px] += sum_k w[o][k] * y[px][k], per wave: 16 px, 96 o ----
#pragma unroll
        for (int sec = 0; sec < 3; ++sec) {
            short8 bfrag = *(const short8*)&y_lds[sec][16 * wv + n][q * 8];
#pragma unroll
            for (int t = 0; t < 6; ++t) {
                short8 afrag = *(const short8*)&w_lds[sec][16 * t + n][q * 8];
                acc[t] = __builtin_amdgcn_mfma_f32_16x16x32_bf16(afrag, bfrag, acc[t], 0, 0, 0);
            }
        }

        __syncthreads();
    }

    // ---- epilogue: C/D layout col=lane&15 (px), row=quad*4+reg (o) ----
    const int row  = wv >> 1;
    const int colb = 16 * (wv & 1) + n;
    const int h    = 2 * by + row;
    const int wc   = 32 * bx + colb;
#pragma unroll
    for (int t = 0; t < 6; ++t) {
#pragma unroll
        for (int r = 0; r < 4; ++r) {
            int o = 16 * t + 4 * q + r;
            out[(size_t)(bz * NC + o) * HW + h * NW + wc] = acc[t][r];
        }
    }
}

extern "C" void kernel_launch(void* const* d_in, const int* in_sizes, int n_in,
                              void* d_out, int out_size, void* d_ws, size_t ws_size,
                              hipStream_t stream) {
    const float* x1 = (const float*)d_in[0];
    const float* x2 = (const float*)d_in[1];
    const float* x3 = (const float*)d_in[2];
    const float* w  = (const float*)d_in[3];
    float* out = (float*)d_out;
    dim3 grid(NW / 32, NH / 2, NB);   // 8 x 128 x 4
    dwt_fused_kernel<<<grid, dim3(256), 0, stream>>>(x1, x2, x3, w, out);
}